// Round 1
// baseline (2153.604 us; speedup 1.0000x reference)
//
#include <hip/hip_runtime.h>

#define SS    4096   // sequence length
#define DK    16     // head dim
#define NB    4      // batch
#define TQ    2      // query rows per block
#define BLOCK 256
#define CHUNK 1024   // k span per chunk (BLOCK threads * 4 k each)
#define NCH   4      // SS / CHUNK
#define KPT   16     // k columns per thread total (NCH * 4)

// ---- runtime mask-dtype probe --------------------------------------------
// int32 mask: every 4-byte word is exactly 0 or 1.
// uint8 mask: words pack 4 bools -> high bytes nonzero w/ prob 7/8 per word.
__global__ void detect_mask_dtype(const unsigned* __restrict__ m,
                                  int* __restrict__ flag)
{
    unsigned acc = 0;
    for (int i = 0; i < 1024; ++i) acc |= m[i];
    *flag = (acc > 1u) ? 1 : 0;    // 1 => byte-packed bools
}

// ---- K/V transpose: [b][s][d] -> [b][d][s] (2 MB total, ~2 us) -----------
// Reads coalesced (float4 per thread), writes coalesced (consecutive threads
// -> consecutive s for each d).
__global__ __launch_bounds__(256)
void transpose_kv(const float* __restrict__ K, const float* __restrict__ V,
                  float* __restrict__ KT, float* __restrict__ VT)
{
    const int t = blockIdx.x * blockDim.x + threadIdx.x;   // b*SS + s
    const int b = t >> 12;
    const int s = t & (SS - 1);

    const float4* kp = (const float4*)(K + (size_t)t * DK);
    const float4* vp = (const float4*)(V + (size_t)t * DK);
    const float4 ka = kp[0], kb = kp[1], kc = kp[2], kd = kp[3];
    const float4 va = vp[0], vb = vp[1], vc = vp[2], vd = vp[3];
    const float kr[DK] = {ka.x, ka.y, ka.z, ka.w, kb.x, kb.y, kb.z, kb.w,
                          kc.x, kc.y, kc.z, kc.w, kd.x, kd.y, kd.z, kd.w};
    const float vr[DK] = {va.x, va.y, va.z, va.w, vb.x, vb.y, vb.z, vb.w,
                          vc.x, vc.y, vc.z, vc.w, vd.x, vd.y, vd.z, vd.w};

    float* ko = KT + (size_t)b * DK * SS + s;
    float* vo = VT + (size_t)b * DK * SS + s;
    #pragma unroll
    for (int d = 0; d < DK; ++d) {
        ko[(size_t)d * SS] = kr[d];
        vo[(size_t)d * SS] = vr[d];
    }
}

// ---- fused attention ------------------------------------------------------
// TR=true : K^T/V^T available in workspace -> all loads coalesced float4.
// TR=false: fallback, original gathered K/V row reads (correct, slower).
template<bool TR>
__global__ __launch_bounds__(BLOCK, 4)
void attn_fused(const float* __restrict__ Qm, const float* __restrict__ Km,
                const float* __restrict__ Vm, const void*  __restrict__ Mraw,
                const float* __restrict__ Lm, const float* __restrict__ WP,
                const float* __restrict__ BP, const int*   __restrict__ flagp,
                const float* __restrict__ KTp, const float* __restrict__ VTp,
                float* __restrict__ Co, float* __restrict__ Ao)
{
    __shared__ float redl[4][TQ];
    __shared__ float redc[4][TQ][DK];

    const int tid = threadIdx.x;
    const int b   = blockIdx.x >> 11;           // 2048 blocks per batch
    const int q0  = (blockIdx.x & 2047) * TQ;

    const bool  m8 = (*flagp != 0);             // block-uniform
    const float sw = WP[0];
    const float sb = BP[0];

    const float* qp = Qm + ((size_t)b * SS + q0) * DK;
    const size_t mrow = (size_t)b * SS * SS + (size_t)q0 * SS;
    const int*           mp32 = (const int*)Mraw           + mrow;
    const unsigned char* mp8  = (const unsigned char*)Mraw + mrow;
    const float* lp = Lm + mrow;
    float*       ap = Ao + mrow;

    const float* kt = KTp + (size_t)b * DK * SS;
    const float* vt = VTp + (size_t)b * DK * SS;
    const float* kp = Km  + (size_t)b * SS * DK;
    const float* vp = Vm  + (size_t)b * SS * DK;

    // ---- Q rows are block-uniform: pin into SGPRs (BIT-CAST, not int conv)
    float qreg[TQ][DK];
    #pragma unroll
    for (int qq = 0; qq < TQ; ++qq)
        #pragma unroll
        for (int d = 0; d < DK; ++d)
            qreg[qq][d] = __uint_as_float(
                __builtin_amdgcn_readfirstlane(__float_as_uint(qp[qq * DK + d])));

    const int kb4 = tid * 4;    // this thread's 4-k base within each chunk

    float p[TQ][KPT];
    float lsum[TQ] = {0.f, 0.f};
    float ctx[TQ][DK];
    #pragma unroll
    for (int qq = 0; qq < TQ; ++qq)
        #pragma unroll
        for (int d = 0; d < DK; ++d)
            ctx[qq][d] = 0.f;

    // ---- fused pass: scores -> exp -> p, lsum, unnormalized ctx ----------
    #pragma unroll
    for (int c = 0; c < NCH; ++c) {
        const int k0 = c * CHUNK + kb4;

        float4 li[TQ];
        #pragma unroll
        for (int qq = 0; qq < TQ; ++qq)
            li[qq] = *(const float4*)(lp + (size_t)qq * SS + k0);

        unsigned mu[TQ];
        int4     mi[TQ];
        if (m8) {
            #pragma unroll
            for (int qq = 0; qq < TQ; ++qq)
                mu[qq] = *(const unsigned*)(mp8 + (size_t)qq * SS + k0);
        } else {
            #pragma unroll
            for (int qq = 0; qq < TQ; ++qq)
                mi[qq] = *(const int4*)(mp32 + (size_t)qq * SS + k0);
        }

        float s[TQ][4];
        #pragma unroll
        for (int qq = 0; qq < TQ; ++qq)
            s[qq][0] = s[qq][1] = s[qq][2] = s[qq][3] = 0.f;

        if (TR) {
            // coalesced: K^T[d][k0..k0+3] is contiguous in k
            #pragma unroll
            for (int d = 0; d < DK; ++d) {
                const float4 k4 = *(const float4*)(kt + (size_t)d * SS + k0);
                #pragma unroll
                for (int qq = 0; qq < TQ; ++qq) {
                    const float q = qreg[qq][d];
                    s[qq][0] = fmaf(q, k4.x, s[qq][0]);
                    s[qq][1] = fmaf(q, k4.y, s[qq][1]);
                    s[qq][2] = fmaf(q, k4.z, s[qq][2]);
                    s[qq][3] = fmaf(q, k4.w, s[qq][3]);
                }
            }
        } else {
            #pragma unroll
            for (int u = 0; u < 4; ++u) {
                const int k = k0 + u;
                const float4 ka = *(const float4*)(kp + (size_t)k * DK + 0);
                const float4 kb = *(const float4*)(kp + (size_t)k * DK + 4);
                const float4 kc = *(const float4*)(kp + (size_t)k * DK + 8);
                const float4 kd = *(const float4*)(kp + (size_t)k * DK + 12);
                const float kr[DK] = {ka.x, ka.y, ka.z, ka.w, kb.x, kb.y, kb.z, kb.w,
                                      kc.x, kc.y, kc.z, kc.w, kd.x, kd.y, kd.z, kd.w};
                #pragma unroll
                for (int qq = 0; qq < TQ; ++qq) {
                    float acc = 0.f;
                    #pragma unroll
                    for (int d = 0; d < DK; ++d)
                        acc = fmaf(qreg[qq][d], kr[d], acc);
                    s[qq][u] = acc;
                }
            }
        }

        float pc[TQ][4];
        #pragma unroll
        for (int u = 0; u < 4; ++u)
            #pragma unroll
            for (int qq = 0; qq < TQ; ++qq) {
                const float lv = (u == 0) ? li[qq].x : (u == 1) ? li[qq].y
                               : (u == 2) ? li[qq].z : li[qq].w;
                const int mv = m8
                    ? (int)((mu[qq] >> (8 * u)) & 0xffu)
                    : ((u == 0) ? mi[qq].x : (u == 1) ? mi[qq].y
                     : (u == 2) ? mi[qq].z : mi[qq].w);
                const float sv = fmaf(s[qq][u], 0.25f, fmaf(sw, lv, sb));
                const float e  = __expf(sv);
                const float pv = mv ? 0.f : e;   // mask==true -> -1e9 -> 0
                pc[qq][u]      = pv;
                p[qq][4 * c + u] = pv;
                lsum[qq] += pv;
            }

        if (TR) {
            // coalesced: V^T[d][k0..k0+3] contiguous in k
            #pragma unroll
            for (int d = 0; d < DK; ++d) {
                const float4 v4 = *(const float4*)(vt + (size_t)d * SS + k0);
                #pragma unroll
                for (int qq = 0; qq < TQ; ++qq) {
                    float a = ctx[qq][d];
                    a = fmaf(pc[qq][0], v4.x, a);
                    a = fmaf(pc[qq][1], v4.y, a);
                    a = fmaf(pc[qq][2], v4.z, a);
                    a = fmaf(pc[qq][3], v4.w, a);
                    ctx[qq][d] = a;
                }
            }
        } else {
            #pragma unroll
            for (int u = 0; u < 4; ++u) {
                const int k = k0 + u;
                const float4 va = *(const float4*)(vp + (size_t)k * DK + 0);
                const float4 vb = *(const float4*)(vp + (size_t)k * DK + 4);
                const float4 vc = *(const float4*)(vp + (size_t)k * DK + 8);
                const float4 vd = *(const float4*)(vp + (size_t)k * DK + 12);
                const float vr[DK] = {va.x, va.y, va.z, va.w, vb.x, vb.y, vb.z, vb.w,
                                      vc.x, vc.y, vc.z, vc.w, vd.x, vd.y, vd.z, vd.w};
                #pragma unroll
                for (int qq = 0; qq < TQ; ++qq)
                    #pragma unroll
                    for (int d = 0; d < DK; ++d)
                        ctx[qq][d] = fmaf(pc[qq][u], vr[d], ctx[qq][d]);
            }
        }
    }

    // ---- row-sum reduction (shuffle within wave, LDS across waves) --------
    const int lane = tid & 63;
    const int wv   = tid >> 6;
    #pragma unroll
    for (int qq = 0; qq < TQ; ++qq) {
        float v = lsum[qq];
        #pragma unroll
        for (int off = 32; off; off >>= 1)
            v += __shfl_down(v, off);
        lsum[qq] = v;
    }
    if (lane == 0) {
        #pragma unroll
        for (int qq = 0; qq < TQ; ++qq)
            redl[wv][qq] = lsum[qq];
    }
    __syncthreads();
    float rl[TQ];
    #pragma unroll
    for (int qq = 0; qq < TQ; ++qq)
        rl[qq] = 1.0f / (redl[0][qq] + redl[1][qq] + redl[2][qq] + redl[3][qq]);

    // ---- attn stores: normalized, 16 B/lane, fully coalesced --------------
    #pragma unroll
    for (int qq = 0; qq < TQ; ++qq) {
        const float r = rl[qq];
        #pragma unroll
        for (int c = 0; c < NCH; ++c) {
            float4 st = {p[qq][4 * c + 0] * r, p[qq][4 * c + 1] * r,
                         p[qq][4 * c + 2] * r, p[qq][4 * c + 3] * r};
            *(float4*)(ap + (size_t)qq * SS + c * CHUNK + kb4) = st;
        }
    }

    // ---- context: scale by 1/rowsum, reduce across threads ----------------
    #pragma unroll
    for (int qq = 0; qq < TQ; ++qq)
        #pragma unroll
        for (int d = 0; d < DK; ++d) {
            float v = ctx[qq][d] * rl[qq];
            #pragma unroll
            for (int off = 32; off; off >>= 1)
                v += __shfl_down(v, off);
            ctx[qq][d] = v;
        }
    if (lane == 0) {
        #pragma unroll
        for (int qq = 0; qq < TQ; ++qq)
            #pragma unroll
            for (int d = 0; d < DK; ++d)
                redc[wv][qq][d] = ctx[qq][d];
    }
    __syncthreads();
    if (tid < TQ * DK) {
        const int qq = tid >> 4;
        const int d  = tid & 15;
        const float v = redc[0][qq][d] + redc[1][qq][d]
                      + redc[2][qq][d] + redc[3][qq][d];
        Co[((size_t)b * SS + q0 + qq) * DK + d] = v;
    }
}

extern "C" void kernel_launch(void* const* d_in, const int* in_sizes, int n_in,
                              void* d_out, int out_size, void* d_ws, size_t ws_size,
                              hipStream_t stream)
{
    (void)in_sizes; (void)n_in; (void)out_size;

    const float* Q  = (const float*)d_in[0];
    const float* K  = (const float*)d_in[1];
    const float* V  = (const float*)d_in[2];
    const void*  M  = d_in[3];
    const float* L  = (const float*)d_in[4];
    const float* W  = (const float*)d_in[5];
    const float* Bp = (const float*)d_in[6];

    // workspace: [flag][pad to 256B][KT 1MB][VT 1MB]
    int*   flag = (int*)d_ws;
    float* KT   = (float*)((char*)d_ws + 256);
    float* VT   = KT + (size_t)NB * DK * SS;
    const size_t need = 256 + 2ull * NB * DK * SS * sizeof(float);
    const bool tr = (ws_size >= need);

    float* Co = (float*)d_out;                              // context [4,1,4096,16]
    float* Ao = (float*)d_out + (size_t)NB * SS * DK;       // attn    [4,1,4096,4096]

    detect_mask_dtype<<<1, 1, 0, stream>>>((const unsigned*)M, flag);

    dim3 grid(NB * SS / TQ);   // 8192 blocks
    dim3 block(BLOCK);
    if (tr) {
        transpose_kv<<<dim3(NB * SS / 256), dim3(256), 0, stream>>>(K, V, KT, VT);
        attn_fused<true><<<grid, block, 0, stream>>>(Q, K, V, M, L, W, Bp, flag,
                                                     KT, VT, Co, Ao);
    } else {
        attn_fused<false><<<grid, block, 0, stream>>>(Q, K, V, M, L, W, Bp, flag,
                                                      KT, VT, Co, Ao);
    }
}

// Round 3
// 844.164 us; speedup vs baseline: 2.5512x; 2.5512x over previous
//
#include <hip/hip_runtime.h>

#define SS    4096   // sequence length
#define DK    16     // head dim
#define NB    4      // batch
#define TQ    4      // query rows per block
#define BLOCK 256
#define CHUNK 1024   // k span per chunk (BLOCK threads * 4 k each)
#define NCH   4      // SS / CHUNK
#define KPT   16     // k columns per thread total (NCH * 4)

// native clang vector types: required by __builtin_nontemporal_load/store
typedef float    f32x4 __attribute__((ext_vector_type(4)));
typedef int      i32x4 __attribute__((ext_vector_type(4)));

// ---- runtime mask-dtype probe --------------------------------------------
// int32 mask: every 4-byte word is exactly 0 or 1.
// uint8 mask: words pack 4 bools -> high bytes nonzero w/ prob 7/8 per word.
__global__ void detect_mask_dtype(const unsigned* __restrict__ m,
                                  int* __restrict__ flag)
{
    unsigned acc = 0;
    for (int i = 0; i < 1024; ++i) acc |= m[i];
    *flag = (acc > 1u) ? 1 : 0;    // 1 => byte-packed bools
}

// ---- K/V transpose: [b][s][d] -> [b][d][s] (2 MB total, ~2 us) -----------
__global__ __launch_bounds__(256)
void transpose_kv(const float* __restrict__ K, const float* __restrict__ V,
                  float* __restrict__ KT, float* __restrict__ VT)
{
    const int t = blockIdx.x * blockDim.x + threadIdx.x;   // b*SS + s
    const int b = t >> 12;
    const int s = t & (SS - 1);

    const f32x4* kp = (const f32x4*)(K + (size_t)t * DK);
    const f32x4* vp = (const f32x4*)(V + (size_t)t * DK);
    const f32x4 ka = kp[0], kb = kp[1], kc = kp[2], kd = kp[3];
    const f32x4 va = vp[0], vb = vp[1], vc = vp[2], vd = vp[3];
    const float kr[DK] = {ka.x, ka.y, ka.z, ka.w, kb.x, kb.y, kb.z, kb.w,
                          kc.x, kc.y, kc.z, kc.w, kd.x, kd.y, kd.z, kd.w};
    const float vr[DK] = {va.x, va.y, va.z, va.w, vb.x, vb.y, vb.z, vb.w,
                          vc.x, vc.y, vc.z, vc.w, vd.x, vd.y, vd.z, vd.w};

    float* ko = KT + (size_t)b * DK * SS + s;
    float* vo = VT + (size_t)b * DK * SS + s;
    #pragma unroll
    for (int d = 0; d < DK; ++d) {
        ko[(size_t)d * SS] = kr[d];
        vo[(size_t)d * SS] = vr[d];
    }
}

// ---- fused attention ------------------------------------------------------
// TR=true : K^T/V^T available in workspace -> all loads coalesced float4.
// TR=false: fallback, gathered K/V row reads (correct, slower).
// NOTE: plain __launch_bounds__(BLOCK) only. A min-waves hint here caps VGPR
// at 128 and spills p[]/ctx[] to scratch (round-1: 6 GB scratch traffic, 3x
// slower). Live state needs ~190 VGPRs; 2 waves/SIMD is the right operating
// point for this kernel.
template<bool TR>
__global__ __launch_bounds__(BLOCK)
void attn_fused(const float* __restrict__ Qm, const float* __restrict__ Km,
                const float* __restrict__ Vm, const void*  __restrict__ Mraw,
                const float* __restrict__ Lm, const float* __restrict__ WP,
                const float* __restrict__ BP, const int*   __restrict__ flagp,
                const float* __restrict__ KTp, const float* __restrict__ VTp,
                float* __restrict__ Co, float* __restrict__ Ao)
{
    __shared__ float redl[4][TQ];
    __shared__ float redc[4][TQ][DK];

    const int tid = threadIdx.x;
    const int b   = blockIdx.x >> 10;           // 1024 blocks per batch
    const int q0  = (blockIdx.x & 1023) * TQ;

    const bool  m8 = (*flagp != 0);             // block-uniform
    const float sw = WP[0];
    const float sb = BP[0];

    const float* qp = Qm + ((size_t)b * SS + q0) * DK;
    const size_t mrow = (size_t)b * SS * SS + (size_t)q0 * SS;
    const int*           mp32 = (const int*)Mraw           + mrow;
    const unsigned char* mp8  = (const unsigned char*)Mraw + mrow;
    const float* lp = Lm + mrow;
    float*       ap = Ao + mrow;

    const float* kt = KTp + (size_t)b * DK * SS;
    const float* vt = VTp + (size_t)b * DK * SS;
    const float* kp = Km  + (size_t)b * SS * DK;
    const float* vp = Vm  + (size_t)b * SS * DK;

    // ---- Q rows are block-uniform: pin into SGPRs (BIT-CAST, not int conv)
    float qreg[TQ][DK];
    #pragma unroll
    for (int qq = 0; qq < TQ; ++qq)
        #pragma unroll
        for (int d = 0; d < DK; ++d)
            qreg[qq][d] = __uint_as_float(
                __builtin_amdgcn_readfirstlane(__float_as_uint(qp[qq * DK + d])));

    const int kb4 = tid * 4;    // this thread's 4-k base within each chunk

    float p[TQ][KPT];
    float lsum[TQ] = {0.f, 0.f, 0.f, 0.f};
    float ctx[TQ][DK];
    #pragma unroll
    for (int qq = 0; qq < TQ; ++qq)
        #pragma unroll
        for (int d = 0; d < DK; ++d)
            ctx[qq][d] = 0.f;

    // ---- fused pass: scores -> exp -> p, lsum, unnormalized ctx ----------
    #pragma unroll
    for (int c = 0; c < NCH; ++c) {
        const int k0 = c * CHUNK + kb4;

        // streaming inputs: non-temporal (never reused; keep KT/VT in L2)
        f32x4 li[TQ];
        #pragma unroll
        for (int qq = 0; qq < TQ; ++qq)
            li[qq] = __builtin_nontemporal_load(
                         (const f32x4*)(lp + (size_t)qq * SS + k0));

        unsigned mu[TQ];
        i32x4    mi[TQ];
        if (m8) {
            #pragma unroll
            for (int qq = 0; qq < TQ; ++qq)
                mu[qq] = __builtin_nontemporal_load(
                             (const unsigned*)(mp8 + (size_t)qq * SS + k0));
        } else {
            #pragma unroll
            for (int qq = 0; qq < TQ; ++qq)
                mi[qq] = __builtin_nontemporal_load(
                             (const i32x4*)(mp32 + (size_t)qq * SS + k0));
        }

        float s[TQ][4];
        #pragma unroll
        for (int qq = 0; qq < TQ; ++qq)
            s[qq][0] = s[qq][1] = s[qq][2] = s[qq][3] = 0.f;

        if (TR) {
            // coalesced: K^T[d][k0..k0+3] contiguous in k (L2-resident)
            #pragma unroll
            for (int d = 0; d < DK; ++d) {
                const f32x4 k4 = *(const f32x4*)(kt + (size_t)d * SS + k0);
                #pragma unroll
                for (int qq = 0; qq < TQ; ++qq) {
                    const float q = qreg[qq][d];
                    s[qq][0] = fmaf(q, k4.x, s[qq][0]);
                    s[qq][1] = fmaf(q, k4.y, s[qq][1]);
                    s[qq][2] = fmaf(q, k4.z, s[qq][2]);
                    s[qq][3] = fmaf(q, k4.w, s[qq][3]);
                }
            }
        } else {
            #pragma unroll
            for (int u = 0; u < 4; ++u) {
                const int k = k0 + u;
                const f32x4 ka = *(const f32x4*)(kp + (size_t)k * DK + 0);
                const f32x4 kb = *(const f32x4*)(kp + (size_t)k * DK + 4);
                const f32x4 kc = *(const f32x4*)(kp + (size_t)k * DK + 8);
                const f32x4 kd = *(const f32x4*)(kp + (size_t)k * DK + 12);
                const float kr[DK] = {ka.x, ka.y, ka.z, ka.w, kb.x, kb.y, kb.z, kb.w,
                                      kc.x, kc.y, kc.z, kc.w, kd.x, kd.y, kd.z, kd.w};
                #pragma unroll
                for (int qq = 0; qq < TQ; ++qq) {
                    float acc = 0.f;
                    #pragma unroll
                    for (int d = 0; d < DK; ++d)
                        acc = fmaf(qreg[qq][d], kr[d], acc);
                    s[qq][u] = acc;
                }
            }
        }

        float pc[TQ][4];
        #pragma unroll
        for (int u = 0; u < 4; ++u)
            #pragma unroll
            for (int qq = 0; qq < TQ; ++qq) {
                const float lv = (u == 0) ? li[qq].x : (u == 1) ? li[qq].y
                               : (u == 2) ? li[qq].z : li[qq].w;
                const int mv = m8
                    ? (int)((mu[qq] >> (8 * u)) & 0xffu)
                    : ((u == 0) ? mi[qq].x : (u == 1) ? mi[qq].y
                     : (u == 2) ? mi[qq].z : mi[qq].w);
                const float sv = fmaf(s[qq][u], 0.25f, fmaf(sw, lv, sb));
                const float e  = __expf(sv);
                const float pv = mv ? 0.f : e;   // mask==true -> -1e9 -> 0
                pc[qq][u]        = pv;
                p[qq][4 * c + u] = pv;
                lsum[qq] += pv;
            }

        if (TR) {
            // coalesced: V^T[d][k0..k0+3] contiguous in k (L2-resident)
            #pragma unroll
            for (int d = 0; d < DK; ++d) {
                const f32x4 v4 = *(const f32x4*)(vt + (size_t)d * SS + k0);
                #pragma unroll
                for (int qq = 0; qq < TQ; ++qq) {
                    float a = ctx[qq][d];
                    a = fmaf(pc[qq][0], v4.x, a);
                    a = fmaf(pc[qq][1], v4.y, a);
                    a = fmaf(pc[qq][2], v4.z, a);
                    a = fmaf(pc[qq][3], v4.w, a);
                    ctx[qq][d] = a;
                }
            }
        } else {
            #pragma unroll
            for (int u = 0; u < 4; ++u) {
                const int k = k0 + u;
                const f32x4 va = *(const f32x4*)(vp + (size_t)k * DK + 0);
                const f32x4 vb = *(const f32x4*)(vp + (size_t)k * DK + 4);
                const f32x4 vc = *(const f32x4*)(vp + (size_t)k * DK + 8);
                const f32x4 vd = *(const f32x4*)(vp + (size_t)k * DK + 12);
                const float vr[DK] = {va.x, va.y, va.z, va.w, vb.x, vb.y, vb.z, vb.w,
                                      vc.x, vc.y, vc.z, vc.w, vd.x, vd.y, vd.z, vd.w};
                #pragma unroll
                for (int qq = 0; qq < TQ; ++qq)
                    #pragma unroll
                    for (int d = 0; d < DK; ++d)
                        ctx[qq][d] = fmaf(pc[qq][u], vr[d], ctx[qq][d]);
            }
        }
    }

    // ---- row-sum reduction (shuffle within wave, LDS across waves) --------
    const int lane = tid & 63;
    const int wv   = tid >> 6;
    #pragma unroll
    for (int qq = 0; qq < TQ; ++qq) {
        float v = lsum[qq];
        #pragma unroll
        for (int off = 32; off; off >>= 1)
            v += __shfl_down(v, off);
        lsum[qq] = v;
    }
    if (lane == 0) {
        #pragma unroll
        for (int qq = 0; qq < TQ; ++qq)
            redl[wv][qq] = lsum[qq];
    }
    __syncthreads();
    float rl[TQ];
    #pragma unroll
    for (int qq = 0; qq < TQ; ++qq)
        rl[qq] = 1.0f / (redl[0][qq] + redl[1][qq] + redl[2][qq] + redl[3][qq]);

    // ---- attn stores: normalized, 16 B/lane, coalesced, non-temporal ------
    #pragma unroll
    for (int qq = 0; qq < TQ; ++qq) {
        const float r = rl[qq];
        #pragma unroll
        for (int c = 0; c < NCH; ++c) {
            f32x4 st = {p[qq][4 * c + 0] * r, p[qq][4 * c + 1] * r,
                        p[qq][4 * c + 2] * r, p[qq][4 * c + 3] * r};
            __builtin_nontemporal_store(
                st, (f32x4*)(ap + (size_t)qq * SS + c * CHUNK + kb4));
        }
    }

    // ---- context: scale by 1/rowsum, reduce across threads ----------------
    #pragma unroll
    for (int qq = 0; qq < TQ; ++qq)
        #pragma unroll
        for (int d = 0; d < DK; ++d) {
            float v = ctx[qq][d] * rl[qq];
            #pragma unroll
            for (int off = 32; off; off >>= 1)
                v += __shfl_down(v, off);
            ctx[qq][d] = v;
        }
    if (lane == 0) {
        #pragma unroll
        for (int qq = 0; qq < TQ; ++qq)
            #pragma unroll
            for (int d = 0; d < DK; ++d)
                redc[wv][qq][d] = ctx[qq][d];
    }
    __syncthreads();
    if (tid < TQ * DK) {
        const int qq = tid >> 4;
        const int d  = tid & 15;
        const float v = redc[0][qq][d] + redc[1][qq][d]
                      + redc[2][qq][d] + redc[3][qq][d];
        Co[((size_t)b * SS + q0 + qq) * DK + d] = v;
    }
}

extern "C" void kernel_launch(void* const* d_in, const int* in_sizes, int n_in,
                              void* d_out, int out_size, void* d_ws, size_t ws_size,
                              hipStream_t stream)
{
    (void)in_sizes; (void)n_in; (void)out_size;

    const float* Q  = (const float*)d_in[0];
    const float* K  = (const float*)d_in[1];
    const float* V  = (const float*)d_in[2];
    const void*  M  = d_in[3];
    const float* L  = (const float*)d_in[4];
    const float* W  = (const float*)d_in[5];
    const float* Bp = (const float*)d_in[6];

    // workspace: [flag][pad to 256B][KT 1MB][VT 1MB]
    int*   flag = (int*)d_ws;
    float* KT   = (float*)((char*)d_ws + 256);
    float* VT   = KT + (size_t)NB * DK * SS;
    const size_t need = 256 + 2ull * NB * DK * SS * sizeof(float);
    const bool tr = (ws_size >= need);

    float* Co = (float*)d_out;                              // context [4,1,4096,16]
    float* Ao = (float*)d_out + (size_t)NB * SS * DK;       // attn    [4,1,4096,4096]

    detect_mask_dtype<<<1, 1, 0, stream>>>((const unsigned*)M, flag);

    dim3 grid(NB * SS / TQ);   // 4096 blocks
    dim3 block(BLOCK);
    if (tr) {
        transpose_kv<<<dim3(NB * SS / 256), dim3(256), 0, stream>>>(K, V, KT, VT);
        attn_fused<true><<<grid, block, 0, stream>>>(Q, K, V, M, L, W, Bp, flag,
                                                     KT, VT, Co, Ao);
    } else {
        attn_fused<false><<<grid, block, 0, stream>>>(Q, K, V, M, L, W, Bp, flag,
                                                      KT, VT, Co, Ao);
    }
}